// Round 10
// baseline (178.542 us; speedup 1.0000x reference)
//
#include <hip/hip_runtime.h>
#include <hip/hip_bf16.h>

// out[b] = dot(user_factors[user_indices[b]], s)
// s[f]   = sum_c item_factors[item_indices[c], f],  F = 64
//
// ONE graph node, 320 blocks, producer->consumer flags:
//   blocks 0..63   (ITEM): gather+sum 256 item rows -> s_part[b][64] via
//                          agent-scope ATOMIC stores (coherence point, not
//                          per-XCD L2), then release-store done[b]=MAGIC.
//   blocks 64..319 (USER): issue 64 user-row gathers FIRST (overlaps the
//                          item phase), acquire-poll the 64 flags, reduce
//                          s_part via agent-scope ATOMIC loads, dot, store.
// Replay invariance (harness tripwire): producer block 0 resets `consumed`
// before publishing; the last consumer block resets all flags to 0, so every
// call (cold / poisoned / replay) does identical wait-then-reduce work.
// Deadlock-free: 320 blocks x 256 thr = 1280 waves << 8192-wave capacity,
// so all blocks are co-resident regardless of dispatch order.

#define FDIM 64
#define NITEM 64
#define NUSER 256
#define NTHREADS 256
#define MAGIC 0x5F3C9A21u

__global__ void __launch_bounds__(NTHREADS)
mf_onepass(const int* __restrict__ user_idx, const int* __restrict__ item_idx,
           const float* __restrict__ user_factors, const float* __restrict__ item_factors,
           float* __restrict__ out, float* s_part, unsigned* done,
           unsigned* consumed, int B) {
    const int lane = threadIdx.x & 63;
    const int wid  = threadIdx.x >> 6;
    const int rg   = lane >> 4;   // row group 0..3
    const int fs   = lane & 15;   // float4 feature slice

    if (blockIdx.x < NITEM) {
        // ================= ITEM producer =================
        if (blockIdx.x == 0 && threadIdx.x == 0)
            __hip_atomic_store(consumed, 0u, __ATOMIC_RELAXED, __HIP_MEMORY_SCOPE_AGENT);

        const int base = blockIdx.x * 256 + wid * 64;   // 256 rows/block
        int idx[16];
        #pragma unroll
        for (int r = 0; r < 16; ++r) {
            const int p = base + r * 4 + rg;
            idx[r] = (p < B) ? item_idx[p] : -1;
        }

        float4 acc = make_float4(0.f, 0.f, 0.f, 0.f);
        #pragma unroll
        for (int r = 0; r < 16; ++r) {
            if (idx[r] >= 0) {
                const float4 v = *(const float4*)(item_factors + (size_t)idx[r] * FDIM + fs * 4);
                acc.x += v.x; acc.y += v.y; acc.z += v.z; acc.w += v.w;
            }
        }
        #pragma unroll
        for (int m = 16; m <= 32; m <<= 1) {
            acc.x += __shfl_xor(acc.x, m);
            acc.y += __shfl_xor(acc.y, m);
            acc.z += __shfl_xor(acc.z, m);
            acc.w += __shfl_xor(acc.w, m);
        }

        __shared__ float4 red[4][16];
        __shared__ float  fin[FDIM];
        if (lane < 16) red[wid][fs] = acc;
        __syncthreads();
        if (threadIdx.x < 16) {
            const float4 a = red[0][threadIdx.x], b = red[1][threadIdx.x],
                         c = red[2][threadIdx.x], d = red[3][threadIdx.x];
            fin[threadIdx.x * 4 + 0] = a.x + b.x + c.x + d.x;
            fin[threadIdx.x * 4 + 1] = a.y + b.y + c.y + d.y;
            fin[threadIdx.x * 4 + 2] = a.z + b.z + c.z + d.z;
            fin[threadIdx.x * 4 + 3] = a.w + b.w + c.w + d.w;
        }
        __syncthreads();
        // Single thread publishes data then flag: program-order release, and
        // agent-scope atomics hit the coherence point (bypass per-XCD L2).
        if (threadIdx.x == 0) {
            float* dst = s_part + blockIdx.x * FDIM;
            for (int f = 0; f < FDIM; ++f)
                __hip_atomic_store(&dst[f], fin[f], __ATOMIC_RELAXED, __HIP_MEMORY_SCOPE_AGENT);
            __hip_atomic_store(&done[blockIdx.x], MAGIC,
                               __ATOMIC_RELEASE, __HIP_MEMORY_SCOPE_AGENT);
        }
    } else {
        // ================= USER consumer =================
        const int ub   = blockIdx.x - NITEM;
        const int base = ub * 64 + wid * 16;            // 64 rows/block

        // 1) issue user gathers immediately (independent of s).
        int p[4], u[4];
        float4 uv[4];
        #pragma unroll
        for (int r = 0; r < 4; ++r) {
            p[r] = base + r * 4 + rg;
            u[r] = (p[r] < B) ? user_idx[p[r]] : -1;
        }
        #pragma unroll
        for (int r = 0; r < 4; ++r)
            uv[r] = (u[r] >= 0)
                ? *(const float4*)(user_factors + (size_t)u[r] * FDIM + fs * 4)
                : make_float4(0.f, 0.f, 0.f, 0.f);

        // 2) acquire-poll all 64 flags (lane l -> flag l).
        for (;;) {
            const unsigned v = __hip_atomic_load(&done[lane],
                                                 __ATOMIC_ACQUIRE, __HIP_MEMORY_SCOPE_AGENT);
            if (__all(v == MAGIC)) break;
            __builtin_amdgcn_s_sleep(2);
        }

        // 3) reduce the 64 s-copies via coherence-point loads.
        __shared__ float sred[4][FDIM];
        __shared__ __align__(16) float s_lds[FDIM];
        {
            const int f = threadIdx.x & 63;   // feature
            const int g = threadIdx.x >> 6;   // copy group 0..3 (16 copies each)
            float a = 0.f;
            #pragma unroll
            for (int j = 0; j < 16; ++j)
                a += __hip_atomic_load(&s_part[(g * 16 + j) * FDIM + f],
                                       __ATOMIC_RELAXED, __HIP_MEMORY_SCOPE_AGENT);
            sred[g][f] = a;
        }
        __syncthreads();   // all 256 threads' s_part reads complete here
        if (threadIdx.x < FDIM)
            s_lds[threadIdx.x] = sred[0][threadIdx.x] + sred[1][threadIdx.x] +
                                 sred[2][threadIdx.x] + sred[3][threadIdx.x];

        // 4) replay invariance: last consumer resets the flags.
        if (threadIdx.x == 64) {   // wave 1: doesn't race the s_lds writes above
            const unsigned c = __hip_atomic_fetch_add(consumed, 1u,
                                                      __ATOMIC_ACQ_REL, __HIP_MEMORY_SCOPE_AGENT);
            if (c == NUSER - 1) {
                for (int i = 0; i < NITEM; ++i)
                    __hip_atomic_store(&done[i], 0u,
                                       __ATOMIC_RELAXED, __HIP_MEMORY_SCOPE_AGENT);
            }
        }
        __syncthreads();
        const float4 s4 = *(const float4*)(s_lds + fs * 4);

        // 5) dots: 16-lane-group shuffle reduce, slice-0 lane writes.
        #pragma unroll
        for (int r = 0; r < 4; ++r) {
            float v = uv[r].x * s4.x + uv[r].y * s4.y + uv[r].z * s4.z + uv[r].w * s4.w;
            v += __shfl_xor(v, 1);
            v += __shfl_xor(v, 2);
            v += __shfl_xor(v, 4);
            v += __shfl_xor(v, 8);
            if (fs == 0 && p[r] < B) out[p[r]] = v;
        }
    }
}

extern "C" void kernel_launch(void* const* d_in, const int* in_sizes, int n_in,
                              void* d_out, int out_size, void* d_ws, size_t ws_size,
                              hipStream_t stream) {
    const int*   user_idx     = (const int*)d_in[0];
    const int*   item_idx     = (const int*)d_in[1];
    const float* user_factors = (const float*)d_in[2];
    const float* item_factors = (const float*)d_in[3];
    float*       out          = (float*)d_out;
    float*       s_part       = (float*)d_ws;                                 // 16 KB
    unsigned*    done         = (unsigned*)((char*)d_ws + NITEM * FDIM * 4);  // 256 B
    unsigned*    consumed     = done + NITEM;                                 // 1 word
    const int B = in_sizes[0];

    mf_onepass<<<NITEM + NUSER, NTHREADS, 0, stream>>>(
        user_idx, item_idx, user_factors, item_factors, out, s_part, done, consumed, B);
}

// Round 11
// 12.827 us; speedup vs baseline: 13.9189x; 13.9189x over previous
//
#include <hip/hip_runtime.h>
#include <hip/hip_bf16.h>

// out[b] = dot(user_factors[user_indices[b]], s)
// s[f]   = sum_c item_factors[item_indices[c], f],  F = 64
//
// 2 graph nodes (kernel boundary = the only cheap device-wide sync; both
// in-kernel sync designs measured 72/178 us due to polling congestion):
//   node 1 mf_item_sum (128 blocks): gather+sum 128 item rows/block
//          -> s_part[128][64] plain stores (no atomics, no memset).
//   node 2 mf_user_dot (512 blocks): issue the 8 user-row gathers FIRST
//          (overlap), then reduce the 128 s-copies (16 MB aggregate L2),
//          then float4 dot + 16-lane shuffle reduce.
// Lane decomposition: rg = lane>>4 (row 0..3), fs = lane&15 (float4 slice)
// -> one dwordx4 wave-instruction covers 4 full 256 B rows, coalesced.

#define FDIM 64
#define NB1 128           // item blocks == number of s copies
#define NB2 512
#define NTHREADS 256
#define WPB 4
#define R1 8              // item rounds/wave: 128*4*8*4 = 16384 rows
#define R2 2              // user rounds/wave: 512*4*2*4 = 16384 rows

__global__ void __launch_bounds__(NTHREADS)
mf_item_sum(const int* __restrict__ item_idx,
            const float* __restrict__ item_factors,
            float* __restrict__ s_part, int B) {
    const int lane = threadIdx.x & 63;
    const int wid  = threadIdx.x >> 6;
    const int rg   = lane >> 4;
    const int fs   = lane & 15;
    const int waveBase = (blockIdx.x * WPB + wid) * (R1 * 4);  // 32 rows/wave

    // Preload indices: all independent, all in flight together.
    int idx[R1];
    #pragma unroll
    for (int r = 0; r < R1; ++r) {
        const int p = waveBase + r * 4 + rg;
        idx[r] = (p < B) ? item_idx[p] : -1;
    }

    float4 acc = make_float4(0.f, 0.f, 0.f, 0.f);
    #pragma unroll
    for (int r = 0; r < R1; ++r) {
        if (idx[r] >= 0) {
            const float4 v = *(const float4*)(item_factors + (size_t)idx[r] * FDIM + fs * 4);
            acc.x += v.x; acc.y += v.y; acc.z += v.z; acc.w += v.w;
        }
    }

    // Sum across the 4 row-groups (lane bits 4,5).
    #pragma unroll
    for (int m = 16; m <= 32; m <<= 1) {
        acc.x += __shfl_xor(acc.x, m);
        acc.y += __shfl_xor(acc.y, m);
        acc.z += __shfl_xor(acc.z, m);
        acc.w += __shfl_xor(acc.w, m);
    }

    // Block reduce across 4 waves, plain-store this block's copy.
    __shared__ float4 red[WPB][16];
    if (lane < 16) red[wid][fs] = acc;
    __syncthreads();
    if (threadIdx.x < 16) {
        const float4 a = red[0][threadIdx.x], b = red[1][threadIdx.x],
                     c = red[2][threadIdx.x], d = red[3][threadIdx.x];
        float4 t;
        t.x = a.x + b.x + c.x + d.x;
        t.y = a.y + b.y + c.y + d.y;
        t.z = a.z + b.z + c.z + d.z;
        t.w = a.w + b.w + c.w + d.w;
        *(float4*)(s_part + blockIdx.x * FDIM + threadIdx.x * 4) = t;
    }
}

__global__ void __launch_bounds__(NTHREADS)
mf_user_dot(const int* __restrict__ user_idx,
            const float* __restrict__ user_factors,
            const float* __restrict__ s_part,
            float* __restrict__ out, int B) {
    const int lane = threadIdx.x & 63;
    const int wid  = threadIdx.x >> 6;
    const int rg   = lane >> 4;
    const int fs   = lane & 15;
    const int waveBase = (blockIdx.x * WPB + wid) * (R2 * 4);  // 8 rows/wave

    // 1) issue user-row gathers FIRST (independent of s).
    int p[R2], u[R2];
    float4 uv[R2];
    #pragma unroll
    for (int r = 0; r < R2; ++r) {
        p[r] = waveBase + r * 4 + rg;
        u[r] = (p[r] < B) ? user_idx[p[r]] : -1;
    }
    #pragma unroll
    for (int r = 0; r < R2; ++r)
        uv[r] = (u[r] >= 0)
            ? *(const float4*)(user_factors + (size_t)u[r] * FDIM + fs * 4)
            : make_float4(0.f, 0.f, 0.f, 0.f);

    // 2) reduce the 128 s-copies (L2-hot) while gathers are in flight.
    //    s_part viewed as [128 copies][16 float4 slices].
    const float4* s_part4 = (const float4*)s_part;
    __shared__ float4 sred[16][16];
    __shared__ float4 s_lds4[16];
    {
        const int cg = threadIdx.x >> 4;     // copy group 0..15 (8 copies each)
        const int sl = threadIdx.x & 15;     // float4 slice
        float4 a = make_float4(0.f, 0.f, 0.f, 0.f);
        #pragma unroll
        for (int j = 0; j < NB1 / 16; ++j) {  // 8 copies
            const float4 v = s_part4[(cg * (NB1 / 16) + j) * 16 + sl];
            a.x += v.x; a.y += v.y; a.z += v.z; a.w += v.w;
        }
        sred[cg][sl] = a;
    }
    __syncthreads();
    if (threadIdx.x < 16) {
        float4 a = make_float4(0.f, 0.f, 0.f, 0.f);
        #pragma unroll
        for (int j = 0; j < 16; ++j) {
            const float4 v = sred[j][threadIdx.x];
            a.x += v.x; a.y += v.y; a.z += v.z; a.w += v.w;
        }
        s_lds4[threadIdx.x] = a;
    }
    __syncthreads();
    const float4 s4 = s_lds4[fs];

    // 3) dots: 16-lane-group shuffle reduce, slice-0 lane writes.
    #pragma unroll
    for (int r = 0; r < R2; ++r) {
        float v = uv[r].x * s4.x + uv[r].y * s4.y + uv[r].z * s4.z + uv[r].w * s4.w;
        v += __shfl_xor(v, 1);
        v += __shfl_xor(v, 2);
        v += __shfl_xor(v, 4);
        v += __shfl_xor(v, 8);
        if (fs == 0 && p[r] < B) out[p[r]] = v;
    }
}

extern "C" void kernel_launch(void* const* d_in, const int* in_sizes, int n_in,
                              void* d_out, int out_size, void* d_ws, size_t ws_size,
                              hipStream_t stream) {
    const int*   user_idx     = (const int*)d_in[0];
    const int*   item_idx     = (const int*)d_in[1];
    const float* user_factors = (const float*)d_in[2];
    const float* item_factors = (const float*)d_in[3];
    float*       out          = (float*)d_out;
    float*       s_part       = (float*)d_ws;   // NB1 * FDIM floats = 32 KB
    const int B = in_sizes[0];

    mf_item_sum<<<NB1, NTHREADS, 0, stream>>>(item_idx, item_factors, s_part, B);
    mf_user_dot<<<NB2, NTHREADS, 0, stream>>>(user_idx, user_factors, s_part, out, B);
}